// Round 16
// baseline (1248.113 us; speedup 1.0000x reference)
//
#include <hip/hip_runtime.h>
#include <hip/hip_bf16.h>
#include <math.h>

// Problem constants
constexpr int V  = 32000;
constexpr int E  = 1024;
constexpr int H  = 16;
constexpr int FF = 4096;
constexpr int L  = 4;
constexpr int B  = 2;
constexpr int C  = 1024;
constexpr int D  = 64;
constexpr int N  = B * C;        // 2048 tokens
constexpr int E3 = 3 * E;        // packed QKV width
constexpr float EPS = 1e-5f;

typedef __hip_bfloat16 bf16;
typedef __bf16 bf16x8 __attribute__((ext_vector_type(8)));
typedef __bf16 bf16x4 __attribute__((ext_vector_type(4)));
typedef float  f32x4  __attribute__((ext_vector_type(4)));

#define AS1 __attribute__((address_space(1)))
#define AS3 __attribute__((address_space(3)))

__device__ inline bf16x8 lds_load8(const bf16* p) {
    bf16x4 lo = *(const bf16x4*)p;
    bf16x4 hi = *(const bf16x4*)(p + 4);
    bf16x8 r;
    r[0]=lo[0]; r[1]=lo[1]; r[2]=lo[2]; r[3]=lo[3];
    r[4]=hi[0]; r[5]=hi[1]; r[6]=hi[2]; r[7]=hi[3];
    return r;
}
__device__ inline void lds_store8(bf16* p, bf16x8 v) {
    bf16x4 lo, hi;
    lo[0]=v[0]; lo[1]=v[1]; lo[2]=v[2]; lo[3]=v[3];
    hi[0]=v[4]; hi[1]=v[5]; hi[2]=v[6]; hi[3]=v[7];
    *(bf16x4*)p = lo; *(bf16x4*)(p + 4) = hi;
}

// BK=32 swizzled fragment read (rows of 32 elems, 4 chunks)
__device__ inline bf16x8 lds_frag32(const bf16* sbase, int row, int c) {
    return *(const bf16x8*)(sbase + row * 32 + ((c ^ ((row >> 1) & 3)) << 3));
}
// BK=64 swizzled fragment read (rows of 64 elems, 8 chunks, slot = c ^ row&7)
__device__ inline bf16x8 lds_frag64(const bf16* sbase, int row, int c) {
    return *(const bf16x8*)(sbase + row * 64 + ((c ^ (row & 7)) << 3));
}

// ---------------------------------------------------------------------------
// Fused embedding + LayerNorm(layer 0): h = embed[x]+pos; hn = LN(h)
// ---------------------------------------------------------------------------
__global__ void embed_ln_kernel(const int* __restrict__ x,
                                const float* __restrict__ embed,
                                const float* __restrict__ pos,
                                const float* __restrict__ w,
                                const float* __restrict__ b,
                                float* __restrict__ h,
                                bf16* __restrict__ hn) {
    __shared__ float red[256];
    int token = blockIdx.x;
    int tid = threadIdx.x;
    int c = token % C;
    int id = x[token];
    float4 ev = ((const float4*)(embed + (size_t)id * E))[tid];
    float4 pv = ((const float4*)(pos + (size_t)c * E))[tid];
    float4 xv;
    xv.x = ev.x + pv.x; xv.y = ev.y + pv.y;
    xv.z = ev.z + pv.z; xv.w = ev.w + pv.w;
    ((float4*)(h + (size_t)token * E))[tid] = xv;

    red[tid] = xv.x + xv.y + xv.z + xv.w;
    __syncthreads();
    for (int st = 128; st > 0; st >>= 1) {
        if (tid < st) red[tid] += red[tid + st];
        __syncthreads();
    }
    float mu = red[0] * (1.0f / E);
    __syncthreads();

    float d0 = xv.x - mu, d1 = xv.y - mu, d2 = xv.z - mu, d3 = xv.w - mu;
    red[tid] = d0 * d0 + d1 * d1 + d2 * d2 + d3 * d3;
    __syncthreads();
    for (int st = 128; st > 0; st >>= 1) {
        if (tid < st) red[tid] += red[tid + st];
        __syncthreads();
    }
    float var = red[0] * (1.0f / E);
    float inv = rsqrtf(var + EPS);

    float4 wv = ((const float4*)w)[tid];
    float4 bv = ((const float4*)b)[tid];
    float y0 = d0 * inv * wv.x + bv.x;
    float y1 = d1 * inv * wv.y + bv.y;
    float y2 = d2 * inv * wv.z + bv.z;
    float y3 = d3 * inv * wv.w + bv.w;
    ushort4 o;
    { bf16 t0 = __float2bfloat16(y0); o.x = *(ushort*)&t0; }
    { bf16 t1 = __float2bfloat16(y1); o.y = *(ushort*)&t1; }
    { bf16 t2 = __float2bfloat16(y2); o.z = *(ushort*)&t2; }
    { bf16 t3 = __float2bfloat16(y3); o.w = *(ushort*)&t3; }
    ((ushort4*)(hn + (size_t)token * E))[tid] = o;
}

// ---------------------------------------------------------------------------
// LayerNorm: f32 in -> bf16 out (float4 vectorized)
// ---------------------------------------------------------------------------
__global__ void layernorm_kernel(const float* __restrict__ in,
                                 const float* __restrict__ w,
                                 const float* __restrict__ b,
                                 bf16* __restrict__ out) {
    __shared__ float red[256];
    int token = blockIdx.x;
    int tid = threadIdx.x;
    float4 xv = ((const float4*)(in + (size_t)token * E))[tid];

    red[tid] = xv.x + xv.y + xv.z + xv.w;
    __syncthreads();
    for (int st = 128; st > 0; st >>= 1) {
        if (tid < st) red[tid] += red[tid + st];
        __syncthreads();
    }
    float mu = red[0] * (1.0f / E);
    __syncthreads();

    float d0 = xv.x - mu, d1 = xv.y - mu, d2 = xv.z - mu, d3 = xv.w - mu;
    red[tid] = d0 * d0 + d1 * d1 + d2 * d2 + d3 * d3;
    __syncthreads();
    for (int st = 128; st > 0; st >>= 1) {
        if (tid < st) red[tid] += red[tid + st];
        __syncthreads();
    }
    float var = red[0] * (1.0f / E);
    float inv = rsqrtf(var + EPS);

    float4 wv = ((const float4*)w)[tid];
    float4 bv = ((const float4*)b)[tid];
    float y0 = d0 * inv * wv.x + bv.x;
    float y1 = d1 * inv * wv.y + bv.y;
    float y2 = d2 * inv * wv.z + bv.z;
    float y3 = d3 * inv * wv.w + bv.w;
    ushort4 o;
    { bf16 t0 = __float2bfloat16(y0); o.x = *(ushort*)&t0; }
    { bf16 t1 = __float2bfloat16(y1); o.y = *(ushort*)&t1; }
    { bf16 t2 = __float2bfloat16(y2); o.z = *(ushort*)&t2; }
    { bf16 t3 = __float2bfloat16(y3); o.w = *(ushort*)&t3; }
    ((ushort4*)(out + (size_t)token * E))[tid] = o;
}

// ---------------------------------------------------------------------------
// ALL weight transposes in one launch (verified round 9)
// ---------------------------------------------------------------------------
__global__ void transpose_all(const float* __restrict__ Wq,
                              const float* __restrict__ Wk,
                              const float* __restrict__ Wv,
                              const float* __restrict__ Wo,
                              const float* __restrict__ W1,
                              const float* __restrict__ W2,
                              const float* __restrict__ Wout,
                              bf16* __restrict__ qkvt, bf16* __restrict__ wot,
                              bf16* __restrict__ w1t,  bf16* __restrict__ w2t,
                              bf16* __restrict__ wvt) {
    __shared__ float tile[64][65];
    int b = blockIdx.x;
    const float* src; bf16* dst;
    int Nn, Kk, n0, k0;
    if (b >= 12288) {
        int rem = b - 12288;
        src = Wout; dst = wvt; Nn = V; Kk = E;
        n0 = (rem % 500) * 64; k0 = (rem / 500) * 64;
    } else {
        int i = b / 3072, r = b % 3072;
        if (r < 1024) {
            int mat = r >> 8, rr = r & 255;
            n0 = (rr & 15) * 64; k0 = (rr >> 4) * 64;
            Nn = E; Kk = E;
            const float* srcs[4] = {Wq, Wk, Wv, Wo};
            src = srcs[mat] + (size_t)i * E * E;
            dst = (mat < 3) ? qkvt + ((size_t)i * E3 + (size_t)mat * E) * E
                            : wot + (size_t)i * E * E;
        } else if (r < 2048) {
            int rr = r - 1024;
            n0 = (rr & 63) * 64; k0 = (rr >> 6) * 64;
            Nn = FF; Kk = E;
            src = W1 + (size_t)i * E * FF;
            dst = w1t + (size_t)i * FF * E;
        } else {
            int rr = r - 2048;
            n0 = (rr & 15) * 64; k0 = (rr >> 4) * 64;
            Nn = E; Kk = FF;
            src = W2 + (size_t)i * FF * E;
            dst = w2t + (size_t)i * E * FF;
        }
    }
    int tid = threadIdx.x;
    #pragma unroll
    for (int it = 0; it < 4; ++it) {
        int idx = it * 256 + tid;
        int row = idx >> 4, c4 = (idx & 15) * 4;
        *(float4*)&tile[row][c4] =
            *(const float4*)&src[(size_t)(k0 + row) * Nn + n0 + c4];
    }
    __syncthreads();
    #pragma unroll
    for (int it = 0; it < 2; ++it) {
        int s = it * 256 + tid;
        int nrow = s >> 3, kc = s & 7;
        bf16x8 v;
        #pragma unroll
        for (int j = 0; j < 8; ++j)
            v[j] = (__bf16)__float2bfloat16(tile[kc * 8 + j][nrow]);
        *(bf16x8*)&dst[(size_t)(n0 + nrow) * Kk + k0 + kc * 8] = v;
    }
}

// ===========================================================================
// 8-PHASE 256x256 GEMM (vocab) — round-13 verified (180us, BK=64, 1 blk/CU).
// ===========================================================================
__launch_bounds__(512, 2)
__global__ void gemm_v8(const bf16* __restrict__ A,
                        const bf16* __restrict__ Bt,
                        const float* __restrict__ bias,
                        float* __restrict__ outF,
                        int M, int Nc, int K) {
    __shared__ __align__(16) bf16 sA[2][2][128 * 64];
    __shared__ __align__(16) bf16 sB[2][2][128 * 64];

    int tid  = threadIdx.x;
    int lane = tid & 63;
    int wid  = tid >> 6;
    int wm   = wid >> 2;
    int wn   = wid & 3;
    int l16  = lane & 15;
    int lhi  = lane >> 4;

    int nwg = gridDim.x * gridDim.y;
    int id  = blockIdx.y * gridDim.x + blockIdx.x;
    int cpx = nwg >> 3;
    int swz = (id & 7) * cpx + (id >> 3);
    int bx  = swz / gridDim.y;
    int by  = swz % gridDim.y;

    size_t brow = (size_t)by * 256;
    size_t bcol = (size_t)bx * 256;

    f32x4 acc[8][4] = {};

    auto stageA = [&](int buf, int half, int t) {
        size_t k0 = (size_t)t * 64;
        #pragma unroll
        for (int j = 0; j < 2; ++j) {
            int s = j * 512 + tid;
            int row = s >> 3;
            int ch  = (s & 7) ^ (row & 7);
            int ldso = (j * 512 + wid * 64) * 8;
            const bf16* g = A + (brow + half * 128 + row) * K + k0 + ch * 8;
            __builtin_amdgcn_global_load_lds(
                (const AS1 void*)g, (AS3 void*)(&sA[buf][half][0] + ldso), 16, 0, 0);
        }
    };
    auto stageB = [&](int buf, int half, int t) {
        size_t k0 = (size_t)t * 64;
        #pragma unroll
        for (int j = 0; j < 2; ++j) {
            int s = j * 512 + tid;
            int row = s >> 3;
            int ch  = (s & 7) ^ (row & 7);
            int ldso = (j * 512 + wid * 64) * 8;
            const bf16* g = Bt + (bcol + half * 128 + row) * K + k0 + ch * 8;
            __builtin_amdgcn_global_load_lds(
                (const AS1 void*)g, (AS3 void*)(&sB[buf][half][0] + ldso), 16, 0, 0);
        }
    };

    int NT = K / 64;
    stageA(0, 0, 0); stageB(0, 0, 0);
    stageB(0, 1, 0); stageA(0, 1, 0);
    stageA(1, 0, 1); stageB(1, 0, 1);

    bf16x8 ra[4][2], rb[2][2], rb0[2][2];

    for (int t = 0; t < NT; ++t) {
        int cur = t & 1, nxt = cur ^ 1;

        // P1
        if (t == NT - 1) asm volatile("s_waitcnt vmcnt(4)" ::: "memory");
        else             asm volatile("s_waitcnt vmcnt(8)" ::: "memory");
        __builtin_amdgcn_sched_barrier(0);
        __builtin_amdgcn_s_barrier();
        if (t + 1 < NT) { stageB(nxt, 1, t + 1); stageA(nxt, 1, t + 1); }
        #pragma unroll
        for (int m = 0; m < 4; ++m)
            #pragma unroll
            for (int kh = 0; kh < 2; ++kh)
                ra[m][kh] = lds_frag64(&sA[cur][0][0], wm * 64 + m * 16 + l16, kh * 4 + lhi);
        #pragma unroll
        for (int n = 0; n < 2; ++n)
            #pragma unroll
            for (int kh = 0; kh < 2; ++kh)
                rb0[n][kh] = lds_frag64(&sB[cur][0][0], wn * 32 + n * 16 + l16, kh * 4 + lhi);
        __builtin_amdgcn_s_setprio(1);
        #pragma unroll
        for (int m = 0; m < 4; ++m)
            #pragma unroll
            for (int n = 0; n < 2; ++n)
                #pragma unroll
                for (int kh = 0; kh < 2; ++kh)
                    acc[m][n] = __builtin_amdgcn_mfma_f32_16x16x32_bf16(
                        ra[m][kh], rb0[n][kh], acc[m][n], 0, 0, 0);
        __builtin_amdgcn_s_setprio(0);

        // P2
        if (t == NT - 1) asm volatile("s_waitcnt vmcnt(0)" ::: "memory");
        else             asm volatile("s_waitcnt vmcnt(8)" ::: "memory");
        __builtin_amdgcn_sched_barrier(0);
        __builtin_amdgcn_s_barrier();
        #pragma unroll
        for (int n = 0; n < 2; ++n)
            #pragma unroll
            for (int kh = 0; kh < 2; ++kh)
                rb[n][kh] = lds_frag64(&sB[cur][1][0], wn * 32 + n * 16 + l16, kh * 4 + lhi);
        __builtin_amdgcn_s_setprio(1);
        #pragma unroll
        for (int m = 0; m < 4; ++m)
            #pragma unroll
            for (int n = 0; n < 2; ++n)
                #pragma unroll
                for (int kh = 0; kh < 2; ++kh)
                    acc[m][n + 2] = __builtin_amdgcn_mfma_f32_16x16x32_bf16(
                        ra[m][kh], rb[n][kh], acc[m][n + 2], 0, 0, 0);
        __builtin_amdgcn_s_setprio(0);

        // P3 — stage {A0,B0}(t+2)
        if (t + 2 < NT) { stageA(cur, 0, t + 2); stageB(cur, 0, t + 2); }
        #pragma unroll
        for (int m = 0; m < 4; ++m)
            #pragma unroll
            for (int kh = 0; kh < 2; ++kh)
                ra[m][kh] = lds_frag64(&sA[cur][1][0], wm * 64 + m * 16 + l16, kh * 4 + lhi);
        __builtin_amdgcn_s_setprio(1);
        #pragma unroll
        for (int m = 0; m < 4; ++m)
            #pragma unroll
            for (int n = 0; n < 2; ++n)
                #pragma unroll
                for (int kh = 0; kh < 2; ++kh)
                    acc[m + 4][n + 2] = __builtin_amdgcn_mfma_f32_16x16x32_bf16(
                        ra[m][kh], rb[n][kh], acc[m + 4][n + 2], 0, 0, 0);
        __builtin_amdgcn_s_setprio(0);

        // P4 — pure MFMA
        __builtin_amdgcn_s_setprio(1);
        #pragma unroll
        for (int m = 0; m < 4; ++m)
            #pragma unroll
            for (int n = 0; n < 2; ++n)
                #pragma unroll
                for (int kh = 0; kh < 2; ++kh)
                    acc[m + 4][n] = __builtin_amdgcn_mfma_f32_16x16x32_bf16(
                        ra[m][kh], rb0[n][kh], acc[m + 4][n], 0, 0, 0);
        __builtin_amdgcn_s_setprio(0);
    }

    int crow = lhi * 4;
    #pragma unroll
    for (int qm = 0; qm < 2; ++qm)
        #pragma unroll
        for (int qn = 0; qn < 2; ++qn)
            #pragma unroll
            for (int m = 0; m < 4; ++m)
                #pragma unroll
                for (int n = 0; n < 2; ++n)
                    #pragma unroll
                    for (int r = 0; r < 4; ++r) {
                        size_t row = brow + qm * 128 + wm * 64 + m * 16 + crow + r;
                        size_t col = bcol + qn * 128 + wn * 32 + n * 16 + l16;
                        float val = acc[qm * 4 + m][qn * 2 + n][r];
                        val += bias[col];
                        outF[row * Nc + col] = val;
                    }
}

// ---------------------------------------------------------------------------
// 128x128 bf16 GEMM, BK=32, ring-of-3 (48 KB LDS -> 3 blocks/CU), prefetch
// depth 2 via post-barrier stage(t+2) (write-safe: (t+2)%3 == (t-1)%3 and
// the barrier orders t-1 reads — verified pattern from gemm_bf16_64).
// Wait ledger: at iteration t's wait only stage(t+1) is outstanding (4
// loads) -> vmcnt(4) guarantees tile t landed; tail vmcnt(0). (QKV, W1)
// ---------------------------------------------------------------------------
__launch_bounds__(256, 3)
__global__ void gemm_bf16_128(const bf16* __restrict__ A,
                              const bf16* __restrict__ Bt,
                              const float* __restrict__ bias,
                              const float* __restrict__ res,
                              float* __restrict__ outF,
                              bf16*  __restrict__ outB,
                              int M, int Nc, int K, int gelu_flag) {
    __shared__ __align__(16) bf16 sA[3][128 * 32];   // 3 x 8 KB
    __shared__ __align__(16) bf16 sB[3][128 * 32];   // 3 x 8 KB

    int tid  = threadIdx.x;
    int lane = tid & 63;
    int wid  = tid >> 6;
    int wr   = wid >> 1;
    int wc   = wid & 1;
    int l16  = lane & 15;
    int lhi  = lane >> 4;

    int nwg = gridDim.x * gridDim.y;
    int id  = blockIdx.y * gridDim.x + blockIdx.x;
    int cpx = nwg >> 3;
    int swz = (id & 7) * cpx + (id >> 3);
    int bx  = swz / gridDim.y;
    int by  = swz % gridDim.y;

    size_t brow = (size_t)by * 128;
    size_t bcol = (size_t)bx * 128;

    f32x4 acc[4][4] = {};

    auto stage = [&](int buf, int t) {
        size_t k0 = (size_t)t * 32;
        #pragma unroll
        for (int j = 0; j < 2; ++j) {
            int s = j * 256 + tid;
            int row = s >> 2;
            int ch  = (s & 3) ^ ((row >> 1) & 3);
            int ldso = (j * 256 + wid * 64) * 8;
            const bf16* ga = A + (brow + row) * K + k0 + ch * 8;
            __builtin_amdgcn_global_load_lds(
                (const AS1 void*)ga, (AS3 void*)(&sA[buf][0] + ldso), 16, 0, 0);
        }
        #pragma unroll
        for (int j = 0; j < 2; ++j) {
            int s = j * 256 + tid;
            int row = s >> 2;
            int ch  = (s & 3) ^ ((row >> 1) & 3);
            int ldso = (j * 256 + wid * 64) * 8;
            const bf16* gb = Bt + (bcol + row) * K + k0 + ch * 8;
            __builtin_amdgcn_global_load_lds(
                (const AS1 void*)gb, (AS3 void*)(&sB[buf][0] + ldso), 16, 0, 0);
        }
    };

    int NT = K / 32;
    stage(0, 0);
    stage(1, 1);
    int cur = 0, sl2 = 2;

    for (int t = 0; t < NT; ++t) {
        if (t == NT - 1) asm volatile("s_waitcnt vmcnt(0)" ::: "memory");
        else             asm volatile("s_waitcnt vmcnt(4)" ::: "memory");
        __builtin_amdgcn_sched_barrier(0);
        __builtin_amdgcn_s_barrier();
        if (t + 2 < NT) stage(sl2, t + 2);   // post-barrier: t-1 reads done

        const bf16* As_ = &sA[cur][0];
        const bf16* Bs_ = &sB[cur][0];
        bf16x8 ra[4], rb[4];
        #pragma unroll
        for (int m = 0; m < 4; ++m)
            ra[m] = lds_frag32(As_, wr * 64 + m * 16 + l16, lhi);
        #pragma unroll
        for (int n = 0; n < 4; ++n)
            rb[n] = lds_frag32(Bs_, wc * 64 + n * 16 + l16, lhi);

        __builtin_amdgcn_s_setprio(1);
        #pragma unroll
        for (int m = 0; m < 4; ++m)
            #pragma unroll
            for (int n = 0; n < 4; ++n)
                acc[m][n] = __builtin_amdgcn_mfma_f32_16x16x32_bf16(
                    ra[m], rb[n], acc[m][n], 0, 0, 0);
        __builtin_amdgcn_s_setprio(0);

        cur = (cur == 2) ? 0 : cur + 1;
        sl2 = (sl2 == 2) ? 0 : sl2 + 1;
    }

    int crow = lhi * 4;
    #pragma unroll
    for (int m = 0; m < 4; ++m) {
        #pragma unroll
        for (int n = 0; n < 4; ++n) {
            #pragma unroll
            for (int r = 0; r < 4; ++r) {
                size_t row = brow + wr * 64 + m * 16 + crow + r;
                size_t col = bcol + wc * 64 + n * 16 + l16;
                float val = acc[m][n][r];
                if (bias) val += bias[col];
                if (gelu_flag) val = 0.5f * val * (1.0f + erff(val * 0.70710678118f));
                if (res) val += res[row * Nc + col];
                if (outF) outF[row * Nc + col] = val;
                if (outB) outB[row * Nc + col] = __float2bfloat16(val);
            }
        }
    }
}

// ---------------------------------------------------------------------------
// 64x128 bf16 GEMM, BK=64, ring-of-3 (verified round 11) (Wo, W2)
// ---------------------------------------------------------------------------
__launch_bounds__(256, 2)
__global__ void gemm_bf16_64(const bf16* __restrict__ A,
                             const bf16* __restrict__ Bt,
                             const float* __restrict__ bias,
                             const float* __restrict__ res,
                             float* __restrict__ outF,
                             bf16*  __restrict__ outB,
                             int M, int Nc, int K, int gelu_flag) {
    __shared__ __align__(16) bf16 sA[3][64 * 64];    // 3 x 8 KB
    __shared__ __align__(16) bf16 sB[3][128 * 64];   // 3 x 16 KB

    int tid  = threadIdx.x;
    int lane = tid & 63;
    int wid  = tid >> 6;
    int l16  = lane & 15;
    int lhi  = lane >> 4;

    int nwg = gridDim.x * gridDim.y;
    int id  = blockIdx.y * gridDim.x + blockIdx.x;
    int cpx = nwg >> 3;
    int swz = (id & 7) * cpx + (id >> 3);
    int bx  = swz / gridDim.y;
    int by  = swz % gridDim.y;

    size_t brow = (size_t)by * 64;
    size_t bcol = (size_t)bx * 128;

    f32x4 acc[4][2] = {};

    auto stage = [&](int buf, int t) {
        size_t k0 = (size_t)t * 64;
        #pragma unroll
        for (int j = 0; j < 2; ++j) {
            int s = j * 256 + tid;
            int row = s >> 3;
            int ch  = (s & 7) ^ (row & 7);
            int ldso = (j * 256 + wid * 64) * 8;
            const bf16* ga = A + (brow + row) * K + k0 + ch * 8;
            __builtin_amdgcn_global_load_lds(
                (const AS1 void*)ga, (AS3 void*)(&sA[buf][0] + ldso), 16, 0, 0);
        }
        #pragma unroll
        for (int j = 0; j < 4; ++j) {
            int s = j * 256 + tid;
            int row = s >> 3;
            int ch  = (s & 7) ^ (row & 7);
            int ldso = (j * 256 + wid * 64) * 8;
            const bf16* gb = Bt + (bcol + row) * K + k0 + ch * 8;
            __builtin_amdgcn_global_load_lds(
                (const AS1 void*)gb, (AS3 void*)(&sB[buf][0] + ldso), 16, 0, 0);
        }
    };

    int NT = K / 64;
    stage(0, 0); stage(1, 1);
    int cur = 0, sl2 = 2;

    for (int t = 0; t < NT; ++t) {
        if (t == NT - 1) asm volatile("s_waitcnt vmcnt(0)" ::: "memory");
        else             asm volatile("s_waitcnt vmcnt(6)" ::: "memory");
        __builtin_amdgcn_sched_barrier(0);
        __builtin_amdgcn_s_barrier();
        if (t + 2 < NT) stage(sl2, t + 2);

        const bf16* As_ = &sA[cur][0];
        const bf16* Bs_ = &sB[cur][0];
        bf16x8 ra[4][2], rb[2][2];
        #pragma unroll
        for (int m = 0; m < 4; ++m)
            #pragma unroll
            for (int kh = 0; kh < 2; ++kh)
                ra[m][kh] = lds_frag64(As_, m * 16 + l16, kh * 4 + lhi);
        #pragma unroll
        for (int n = 0; n < 2; ++n)
            #pragma unroll
            for (int kh = 0; kh < 2; ++kh)
                rb[n][kh] = lds_frag64(Bs_, wid * 32 + n * 16 + l16, kh * 4 + lhi);

        __builtin_amdgcn_s_setprio(1);
        #pragma unroll
        for (int m = 0; m < 4; ++m)
            #pragma unroll
            for (int n = 0; n < 2; ++n)
                #pragma unroll
                for (int kh = 0; kh < 2; ++kh)
                    acc[m][n] = __builtin_amdgcn_mfma_f32_16x16x32_bf16(
                        ra[m][kh], rb[n][kh], acc[m][n], 0, 0, 0);
        __builtin_amdgcn_s_setprio(0);

        cur = (cur == 2) ? 0 : cur + 1;
        sl2 = (sl2 == 2) ? 0 : sl2 + 1;
    }

    int crow = lhi * 4;
    #pragma unroll
    for (int m = 0; m < 4; ++m) {
        #pragma unroll
        for (int n = 0; n < 2; ++n) {
            #pragma unroll
            for (int r = 0; r < 4; ++r) {
                size_t row = brow + m * 16 + crow + r;
                size_t col = bcol + wid * 32 + n * 16 + l16;
                float val = acc[m][n][r];
                if (bias) val += bias[col];
                if (gelu_flag) val = 0.5f * val * (1.0f + erff(val * 0.70710678118f));
                if (res) val += res[row * Nc + col];
                if (outF) outF[row * Nc + col] = val;
                if (outB) outB[row * Nc + col] = __float2bfloat16(val);
            }
        }
    }
}

// ---------------------------------------------------------------------------
// Flash attention (round 15): fused V-transpose staging, balance swizzle,
// reg-staged K/V prefetch. QBLK=64, 4 waves.
// ---------------------------------------------------------------------------
constexpr int QBLK = 64;
constexpr int KVB  = 64;
constexpr int PSTR = 72;

__launch_bounds__(256)
__global__ void flash_attn(const bf16* __restrict__ qkv,
                           bf16* __restrict__ O) {
    __shared__ bf16 sK[KVB][PSTR];
    __shared__ bf16 sV[D][PSTR];
    __shared__ bf16 sP[4][16][PSTR];

    int qt = blockIdx.x;
    int bh = blockIdx.y;
    if (bh & 1) qt = (C / QBLK - 1) - qt;
    int bb = bh >> 4, hh = bh & 15;
    int qbase = qt * QBLK;
    int tid = threadIdx.x, lane = tid & 63, w = tid >> 6;
    int l16 = lane & 15, lhi = lane >> 4;

    int qrow = qbase + w * 16 + l16;
    const bf16* qp = qkv + (size_t)(bb * C + qrow) * E3 + hh * D + lhi * 8;
    bf16x8 qf0 = *(const bf16x8*)qp;
    bf16x8 qf1 = *(const bf16x8*)(qp + 32);

    f32x4 oa[4] = {};
    float m_run[4] = {-INFINITY, -INFINITY, -INFINITY, -INFINITY};
    float l_run[4] = {0.f, 0.f, 0.f, 0.f};

    int NTk = qt + 1;
    int srow = tid >> 3, sc8 = tid & 7;
    int srow2 = srow + 32;
    int c1 = srow  ^ (sc8 << 3);
    int c2 = srow2 ^ (sc8 << 3);

    bf16x8 kvR0, kvR1, vvR0, vvR1;
    kvR0 = *(const bf16x8*)(qkv + (size_t)(bb * C + srow)  * E3 + E + hh * D + sc8 * 8);
    kvR1 = *(const bf16x8*)(qkv + (size_t)(bb * C + srow2) * E3 + E + hh * D + sc8 * 8);
    vvR0 = *(const bf16x8*)(qkv + (size_t)(bb * C + srow)  * E3 + 2 * E + hh * D + sc8 * 8);
    vvR1 = *(const bf16x8*)(qkv + (size_t)(bb * C + srow2) * E3 + 2 * E + hh * D + sc8 * 8);

    for (int t = 0; t < NTk; ++t) {
        __syncthreads();
        lds_store8(&sK[srow][sc8 * 8],  kvR0);
        lds_store8(&sK[srow2][sc8 * 8], kvR1);
        #pragma unroll
        for (int j = 0; j < 8; ++j) {
            *((__bf16*)&sV[sc8 * 8 + j][c1]) = vvR0[j];
            *((__bf16*)&sV[sc8 * 8 + j][c2]) = vvR1[j];
        }

        bf16x8 kvN0, kvN1, vvN0, vvN1;
        if (t + 1 < NTk) {
            int k0n = (t + 1) * KVB;
            kvN0 = *(const bf16x8*)(qkv + (size_t)(bb * C + k0n + srow)  * E3 + E + hh * D + sc8 * 8);
            kvN1 = *(const bf16x8*)(qkv + (size_t)(bb * C + k0n + srow2) * E3 + E + hh * D + sc8 * 8);
            vvN0 = *(const bf16x8*)(qkv + (size_t)(bb * C + k0n + srow)  * E3 + 2 * E + hh * D + sc8 * 8);
            vvN1 = *(const bf16x8*)(qkv + (size_t)(bb * C + k0n + srow2) * E3 + 2 * E + hh * D + sc8 * 8);
        }
        __syncthreads();

        int k0 = t * KVB;
        f32x4 sc[4] = {};
        #pragma unroll
        for (int n = 0; n < 4; ++n) {
            bf16x8 kf0 = lds_load8(&sK[n * 16 + l16][lhi * 8]);
            sc[n] = __builtin_amdgcn_mfma_f32_16x16x32_bf16(qf0, kf0, sc[n], 0, 0, 0);
            bf16x8 kf1 = lds_load8(&sK[n * 16 + l16][32 + lhi * 8]);
            sc[n] = __builtin_amdgcn_mfma_f32_16x16x32_bf16(qf1, kf1, sc[n], 0, 0, 0);
        }

        int qg = qbase + w * 16 + lhi * 4;
        #pragma unroll
        for (int n = 0; n < 4; ++n) {
            int kg = k0 + n * 16 + l16;
            #pragma unroll
            for (int r = 0; r < 4; ++r) {
                float vvv = sc[n][r] * 0.125f;
                if (t == qt && kg > qg + r) vvv = -1e30f;
                sc[n][r] = vvv;
            }
        }

        float pm[4];
        #pragma unroll
        for (int r = 0; r < 4; ++r)
            pm[r] = fmaxf(fmaxf(sc[0][r], sc[1][r]), fmaxf(sc[2][r], sc[3][r]));
        #pragma unroll
        for (int xm = 1; xm <= 8; xm <<= 1)
            #pragma unroll
            for (int r = 0; r < 4; ++r)
                pm[r] = fmaxf(pm[r], __shfl_xor(pm[r], xm));

        float corr[4];
        #pragma unroll
        for (int r = 0; r < 4; ++r) {
            float mn = fmaxf(m_run[r], pm[r]);
            corr[r] = __expf(m_run[r] - mn);
            m_run[r] = mn;
        }
        f32x4 p[4];
        #pragma unroll
        for (int n = 0; n < 4; ++n)
            #pragma unroll
            for (int r = 0; r < 4; ++r)
                p[n][r] = __expf(sc[n][r] - m_run[r]);

        float rsum[4];
        #pragma unroll
        for (int r = 0; r < 4; ++r)
            rsum[r] = p[0][r] + p[1][r] + p[2][r] + p[3][r];
        #pragma unroll
        for (int xm = 1; xm <= 8; xm <<= 1)
            #pragma unroll
            for (int r = 0; r < 4; ++r)
                rsum[r] += __shfl_xor(rsum[r], xm);
        #pragma unroll
        for (int r = 0; r < 4; ++r)
            l_run[r] = l_run[r] * corr[r] + rsum[r];
        #pragma unroll
        for (int nd = 0; nd < 4; ++nd)
            #pragma unroll
            for (int r = 0; r < 4; ++r)
                oa[nd][r] *= corr[r];

        #pragma unroll
        for (int n = 0; n < 4; ++n)
            #pragma unroll
            for (int r = 0; r < 4; ++r)
                sP[w][lhi * 4 + r][n * 16 + l16] = __float2bfloat16(p[n][r]);
        bf16x8 pa0 = lds_load8(&sP[w][l16][lhi * 8]);
        bf16x8 pa1 = lds_load8(&sP[w][l16][32 + lhi * 8]);

        #pragma unroll
        for (int nd = 0; nd < 4; ++nd) {
            int d0 = nd * 16 + l16;
            int dsw = ((nd * 2 + (l16 >> 3)) & 7) << 3;
            bf16x8 vf0 = lds_load8(&sV[d0][(lhi * 8) ^ dsw]);
            oa[nd] = __builtin_amdgcn_mfma_f32_16x16x32_bf16(pa0, vf0, oa[nd], 0, 0, 0);
            bf16x8 vf1 = lds_load8(&sV[d0][(32 + lhi * 8) ^ dsw]);
            oa[nd] = __builtin_amdgcn_mfma_f32_16x16x32_bf16(pa1, vf1, oa[nd], 0, 0, 0);
        }

        if (t + 1 < NTk) { kvR0 = kvN0; kvR1 = kvN1; vvR0 = vvN0; vvR1 = vvN1; }
    }

    #pragma unroll
    for (int r = 0; r < 4; ++r) {
        float inv = 1.0f / l_run[r];
        int qg = qbase + w * 16 + lhi * 4 + r;
        bf16* orow = O + (size_t)(bb * C + qg) * E + hh * D;
        #pragma unroll
        for (int nd = 0; nd < 4; ++nd)
            orow[nd * 16 + l16] = __float2bfloat16(oa[nd][r] * inv);
    }
}

// ---------------------------------------------------------------------------
extern "C" void kernel_launch(void* const* d_in, const int* in_sizes, int n_in,
                              void* d_out, int out_size, void* d_ws, size_t ws_size,
                              hipStream_t stream) {
    const int*   x     = (const int*)  d_in[0];
    const float* embed = (const float*)d_in[1];
    const float* pos   = (const float*)d_in[2];
    const float* Wq    = (const float*)d_in[3];
    const float* Wk    = (const float*)d_in[4];
    const float* Wv    = (const float*)d_in[5];
    const float* Wo    = (const float*)d_in[6];
    const float* ln1w  = (const float*)d_in[7];
    const float* ln1b  = (const float*)d_in[8];
    const float* ln2w  = (const float*)d_in[9];
    const float* ln2b  = (const float*)d_in[10];
    const float* W1    = (const float*)d_in[11];
    const float* b1    = (const float*)d_in[12];
    const float* W2    = (const float*)d_in[13];
    const float* b2    = (const float*)d_in[14];
    const float* lnfw  = (const float*)d_in[15];
    const float* lnfb  = (const float*)d_in[16];
    const float* Wout  = (const float*)d_in[17];
    const float* bout  = (const float*)d_in[18];
    float* out = (float*)d_out;

    char* p = (char*)d_ws;
    auto alloc = [&](size_t bytes) {
        char* r = p;
        p += (bytes + 255) & ~(size_t)255;
        return r;
    };
    float* h    = (float*)alloc((size_t)N * E  * 4);
    bf16*  qkvb = (bf16*) alloc((size_t)N * E3 * 2);
    bf16*  hn   = (bf16*) alloc((size_t)N * E  * 2);
    bf16*  attn = (bf16*) alloc((size_t)N * E  * 2);
    bf16*  ff   = (bf16*) alloc((size_t)N * FF * 2);
    bf16*  qkvt = (bf16*) alloc((size_t)L * E3 * E * 2);
    bf16*  wot  = (bf16*) alloc((size_t)L * E  * E * 2);
    bf16*  w1t  = (bf16*) alloc((size_t)L * FF * E * 2);
    bf16*  w2t  = (bf16*) alloc((size_t)L * E  * FF * 2);
    bf16*  wvt  = (bf16*) alloc((size_t)V * E  * 2 + 4096);

    transpose_all<<<20288, 256, 0, stream>>>(Wq, Wk, Wv, Wo, W1, W2, Wout,
                                             qkvt, wot, w1t, w2t, wvt);

    embed_ln_kernel<<<N, 256, 0, stream>>>(x, embed, pos, ln1w, ln1b, h, hn);

    dim3 gQKV(E3 / 128, N / 128);   // (24, 16) = 384 blocks
    dim3 gF  (FF / 128, N / 128);   // (32, 16) = 512
    dim3 gV  (V  / 256, N / 256);   // (125, 8) = 1000, 8-phase 256^2 BK=64
    dim3 gO  (E  / 128, N / 64);    // (8, 32)  = 256, BK=64 ring-3

    for (int i = 0; i < L; ++i) {
        if (i > 0)
            layernorm_kernel<<<N, 256, 0, stream>>>(h, ln1w + i * E, ln1b + i * E, hn);

        gemm_bf16_128<<<gQKV, 256, 0, stream>>>(hn, qkvt + (size_t)i * E3 * E,
                                                nullptr, nullptr, nullptr, qkvb,
                                                N, E3, E, 0);

        flash_attn<<<dim3(C / QBLK, B * H), 256, 0, stream>>>(qkvb, attn);

        gemm_bf16_64<<<gO, 256, 0, stream>>>(attn, wot + (size_t)i * E * E,
                                             nullptr, h, h, nullptr,
                                             N, E, E, 0);

        layernorm_kernel<<<N, 256, 0, stream>>>(h, ln2w + i * E, ln2b + i * E, hn);

        gemm_bf16_128<<<gF, 256, 0, stream>>>(hn, w1t + (size_t)i * FF * E,
                                              b1 + (size_t)i * FF, nullptr,
                                              nullptr, ff,
                                              N, FF, E, 1);
        gemm_bf16_64<<<gO, 256, 0, stream>>>(ff, w2t + (size_t)i * E * FF,
                                             b2 + (size_t)i * E, h, h, nullptr,
                                             N, E, FF, 0);
    }

    layernorm_kernel<<<N, 256, 0, stream>>>(h, lnfw, lnfb, hn);
    gemm_v8<<<gV, 512, 0, stream>>>(hn, wvt, bout, out, N, V, E);
}

// Round 17
// 1218.706 us; speedup vs baseline: 1.0241x; 1.0241x over previous
//
#include <hip/hip_runtime.h>
#include <hip/hip_bf16.h>
#include <math.h>

// Problem constants
constexpr int V  = 32000;
constexpr int E  = 1024;
constexpr int H  = 16;
constexpr int FF = 4096;
constexpr int L  = 4;
constexpr int B  = 2;
constexpr int C  = 1024;
constexpr int D  = 64;
constexpr int N  = B * C;        // 2048 tokens
constexpr int E3 = 3 * E;        // packed QKV width
constexpr float EPS = 1e-5f;

typedef __hip_bfloat16 bf16;
typedef __bf16 bf16x8 __attribute__((ext_vector_type(8)));
typedef __bf16 bf16x4 __attribute__((ext_vector_type(4)));
typedef float  f32x4  __attribute__((ext_vector_type(4)));

#define AS1 __attribute__((address_space(1)))
#define AS3 __attribute__((address_space(3)))

__device__ inline bf16x8 lds_load8(const bf16* p) {
    bf16x4 lo = *(const bf16x4*)p;
    bf16x4 hi = *(const bf16x4*)(p + 4);
    bf16x8 r;
    r[0]=lo[0]; r[1]=lo[1]; r[2]=lo[2]; r[3]=lo[3];
    r[4]=hi[0]; r[5]=hi[1]; r[6]=hi[2]; r[7]=hi[3];
    return r;
}
__device__ inline void lds_store8(bf16* p, bf16x8 v) {
    bf16x4 lo, hi;
    lo[0]=v[0]; lo[1]=v[1]; lo[2]=v[2]; lo[3]=v[3];
    hi[0]=v[4]; hi[1]=v[5]; hi[2]=v[6]; hi[3]=v[7];
    *(bf16x4*)p = lo; *(bf16x4*)(p + 4) = hi;
}

// BK=32 swizzled fragment read (rows of 32 elems, 4 chunks)
__device__ inline bf16x8 lds_frag32(const bf16* sbase, int row, int c) {
    return *(const bf16x8*)(sbase + row * 32 + ((c ^ ((row >> 1) & 3)) << 3));
}
// BK=64 swizzled fragment read (rows of 64 elems, 8 chunks, slot = c ^ row&7)
__device__ inline bf16x8 lds_frag64(const bf16* sbase, int row, int c) {
    return *(const bf16x8*)(sbase + row * 64 + ((c ^ (row & 7)) << 3));
}

// ---------------------------------------------------------------------------
// Fused embedding + LayerNorm(layer 0): h = embed[x]+pos; hn = LN(h)
// ---------------------------------------------------------------------------
__global__ void embed_ln_kernel(const int* __restrict__ x,
                                const float* __restrict__ embed,
                                const float* __restrict__ pos,
                                const float* __restrict__ w,
                                const float* __restrict__ b,
                                float* __restrict__ h,
                                bf16* __restrict__ hn) {
    __shared__ float red[256];
    int token = blockIdx.x;
    int tid = threadIdx.x;
    int c = token % C;
    int id = x[token];
    float4 ev = ((const float4*)(embed + (size_t)id * E))[tid];
    float4 pv = ((const float4*)(pos + (size_t)c * E))[tid];
    float4 xv;
    xv.x = ev.x + pv.x; xv.y = ev.y + pv.y;
    xv.z = ev.z + pv.z; xv.w = ev.w + pv.w;
    ((float4*)(h + (size_t)token * E))[tid] = xv;

    red[tid] = xv.x + xv.y + xv.z + xv.w;
    __syncthreads();
    for (int st = 128; st > 0; st >>= 1) {
        if (tid < st) red[tid] += red[tid + st];
        __syncthreads();
    }
    float mu = red[0] * (1.0f / E);
    __syncthreads();

    float d0 = xv.x - mu, d1 = xv.y - mu, d2 = xv.z - mu, d3 = xv.w - mu;
    red[tid] = d0 * d0 + d1 * d1 + d2 * d2 + d3 * d3;
    __syncthreads();
    for (int st = 128; st > 0; st >>= 1) {
        if (tid < st) red[tid] += red[tid + st];
        __syncthreads();
    }
    float var = red[0] * (1.0f / E);
    float inv = rsqrtf(var + EPS);

    float4 wv = ((const float4*)w)[tid];
    float4 bv = ((const float4*)b)[tid];
    float y0 = d0 * inv * wv.x + bv.x;
    float y1 = d1 * inv * wv.y + bv.y;
    float y2 = d2 * inv * wv.z + bv.z;
    float y3 = d3 * inv * wv.w + bv.w;
    ushort4 o;
    { bf16 t0 = __float2bfloat16(y0); o.x = *(ushort*)&t0; }
    { bf16 t1 = __float2bfloat16(y1); o.y = *(ushort*)&t1; }
    { bf16 t2 = __float2bfloat16(y2); o.z = *(ushort*)&t2; }
    { bf16 t3 = __float2bfloat16(y3); o.w = *(ushort*)&t3; }
    ((ushort4*)(hn + (size_t)token * E))[tid] = o;
}

// ---------------------------------------------------------------------------
// LayerNorm: f32 in -> bf16 out (float4 vectorized)
// ---------------------------------------------------------------------------
__global__ void layernorm_kernel(const float* __restrict__ in,
                                 const float* __restrict__ w,
                                 const float* __restrict__ b,
                                 bf16* __restrict__ out) {
    __shared__ float red[256];
    int token = blockIdx.x;
    int tid = threadIdx.x;
    float4 xv = ((const float4*)(in + (size_t)token * E))[tid];

    red[tid] = xv.x + xv.y + xv.z + xv.w;
    __syncthreads();
    for (int st = 128; st > 0; st >>= 1) {
        if (tid < st) red[tid] += red[tid + st];
        __syncthreads();
    }
    float mu = red[0] * (1.0f / E);
    __syncthreads();

    float d0 = xv.x - mu, d1 = xv.y - mu, d2 = xv.z - mu, d3 = xv.w - mu;
    red[tid] = d0 * d0 + d1 * d1 + d2 * d2 + d3 * d3;
    __syncthreads();
    for (int st = 128; st > 0; st >>= 1) {
        if (tid < st) red[tid] += red[tid + st];
        __syncthreads();
    }
    float var = red[0] * (1.0f / E);
    float inv = rsqrtf(var + EPS);

    float4 wv = ((const float4*)w)[tid];
    float4 bv = ((const float4*)b)[tid];
    float y0 = d0 * inv * wv.x + bv.x;
    float y1 = d1 * inv * wv.y + bv.y;
    float y2 = d2 * inv * wv.z + bv.z;
    float y3 = d3 * inv * wv.w + bv.w;
    ushort4 o;
    { bf16 t0 = __float2bfloat16(y0); o.x = *(ushort*)&t0; }
    { bf16 t1 = __float2bfloat16(y1); o.y = *(ushort*)&t1; }
    { bf16 t2 = __float2bfloat16(y2); o.z = *(ushort*)&t2; }
    { bf16 t3 = __float2bfloat16(y3); o.w = *(ushort*)&t3; }
    ((ushort4*)(out + (size_t)token * E))[tid] = o;
}

// ---------------------------------------------------------------------------
// ALL weight transposes in one launch (verified round 9)
// ---------------------------------------------------------------------------
__global__ void transpose_all(const float* __restrict__ Wq,
                              const float* __restrict__ Wk,
                              const float* __restrict__ Wv,
                              const float* __restrict__ Wo,
                              const float* __restrict__ W1,
                              const float* __restrict__ W2,
                              const float* __restrict__ Wout,
                              bf16* __restrict__ qkvt, bf16* __restrict__ wot,
                              bf16* __restrict__ w1t,  bf16* __restrict__ w2t,
                              bf16* __restrict__ wvt) {
    __shared__ float tile[64][65];
    int b = blockIdx.x;
    const float* src; bf16* dst;
    int Nn, Kk, n0, k0;
    if (b >= 12288) {
        int rem = b - 12288;
        src = Wout; dst = wvt; Nn = V; Kk = E;
        n0 = (rem % 500) * 64; k0 = (rem / 500) * 64;
    } else {
        int i = b / 3072, r = b % 3072;
        if (r < 1024) {
            int mat = r >> 8, rr = r & 255;
            n0 = (rr & 15) * 64; k0 = (rr >> 4) * 64;
            Nn = E; Kk = E;
            const float* srcs[4] = {Wq, Wk, Wv, Wo};
            src = srcs[mat] + (size_t)i * E * E;
            dst = (mat < 3) ? qkvt + ((size_t)i * E3 + (size_t)mat * E) * E
                            : wot + (size_t)i * E * E;
        } else if (r < 2048) {
            int rr = r - 1024;
            n0 = (rr & 63) * 64; k0 = (rr >> 6) * 64;
            Nn = FF; Kk = E;
            src = W1 + (size_t)i * E * FF;
            dst = w1t + (size_t)i * FF * E;
        } else {
            int rr = r - 2048;
            n0 = (rr & 15) * 64; k0 = (rr >> 4) * 64;
            Nn = E; Kk = FF;
            src = W2 + (size_t)i * FF * E;
            dst = w2t + (size_t)i * E * FF;
        }
    }
    int tid = threadIdx.x;
    #pragma unroll
    for (int it = 0; it < 4; ++it) {
        int idx = it * 256 + tid;
        int row = idx >> 4, c4 = (idx & 15) * 4;
        *(float4*)&tile[row][c4] =
            *(const float4*)&src[(size_t)(k0 + row) * Nn + n0 + c4];
    }
    __syncthreads();
    #pragma unroll
    for (int it = 0; it < 2; ++it) {
        int s = it * 256 + tid;
        int nrow = s >> 3, kc = s & 7;
        bf16x8 v;
        #pragma unroll
        for (int j = 0; j < 8; ++j)
            v[j] = (__bf16)__float2bfloat16(tile[kc * 8 + j][nrow]);
        *(bf16x8*)&dst[(size_t)(n0 + nrow) * Kk + k0 + kc * 8] = v;
    }
}

// ===========================================================================
// 8-PHASE 256x256 GEMM (vocab) — round-13 verified (180us, BK=64, 1 blk/CU).
// ===========================================================================
__launch_bounds__(512, 2)
__global__ void gemm_v8(const bf16* __restrict__ A,
                        const bf16* __restrict__ Bt,
                        const float* __restrict__ bias,
                        float* __restrict__ outF,
                        int M, int Nc, int K) {
    __shared__ __align__(16) bf16 sA[2][2][128 * 64];
    __shared__ __align__(16) bf16 sB[2][2][128 * 64];

    int tid  = threadIdx.x;
    int lane = tid & 63;
    int wid  = tid >> 6;
    int wm   = wid >> 2;
    int wn   = wid & 3;
    int l16  = lane & 15;
    int lhi  = lane >> 4;

    int nwg = gridDim.x * gridDim.y;
    int id  = blockIdx.y * gridDim.x + blockIdx.x;
    int cpx = nwg >> 3;
    int swz = (id & 7) * cpx + (id >> 3);
    int bx  = swz / gridDim.y;
    int by  = swz % gridDim.y;

    size_t brow = (size_t)by * 256;
    size_t bcol = (size_t)bx * 256;

    f32x4 acc[8][4] = {};

    auto stageA = [&](int buf, int half, int t) {
        size_t k0 = (size_t)t * 64;
        #pragma unroll
        for (int j = 0; j < 2; ++j) {
            int s = j * 512 + tid;
            int row = s >> 3;
            int ch  = (s & 7) ^ (row & 7);
            int ldso = (j * 512 + wid * 64) * 8;
            const bf16* g = A + (brow + half * 128 + row) * K + k0 + ch * 8;
            __builtin_amdgcn_global_load_lds(
                (const AS1 void*)g, (AS3 void*)(&sA[buf][half][0] + ldso), 16, 0, 0);
        }
    };
    auto stageB = [&](int buf, int half, int t) {
        size_t k0 = (size_t)t * 64;
        #pragma unroll
        for (int j = 0; j < 2; ++j) {
            int s = j * 512 + tid;
            int row = s >> 3;
            int ch  = (s & 7) ^ (row & 7);
            int ldso = (j * 512 + wid * 64) * 8;
            const bf16* g = Bt + (bcol + half * 128 + row) * K + k0 + ch * 8;
            __builtin_amdgcn_global_load_lds(
                (const AS1 void*)g, (AS3 void*)(&sB[buf][half][0] + ldso), 16, 0, 0);
        }
    };

    int NT = K / 64;
    stageA(0, 0, 0); stageB(0, 0, 0);
    stageB(0, 1, 0); stageA(0, 1, 0);
    stageA(1, 0, 1); stageB(1, 0, 1);

    bf16x8 ra[4][2], rb[2][2], rb0[2][2];

    for (int t = 0; t < NT; ++t) {
        int cur = t & 1, nxt = cur ^ 1;

        // P1
        if (t == NT - 1) asm volatile("s_waitcnt vmcnt(4)" ::: "memory");
        else             asm volatile("s_waitcnt vmcnt(8)" ::: "memory");
        __builtin_amdgcn_sched_barrier(0);
        __builtin_amdgcn_s_barrier();
        if (t + 1 < NT) { stageB(nxt, 1, t + 1); stageA(nxt, 1, t + 1); }
        #pragma unroll
        for (int m = 0; m < 4; ++m)
            #pragma unroll
            for (int kh = 0; kh < 2; ++kh)
                ra[m][kh] = lds_frag64(&sA[cur][0][0], wm * 64 + m * 16 + l16, kh * 4 + lhi);
        #pragma unroll
        for (int n = 0; n < 2; ++n)
            #pragma unroll
            for (int kh = 0; kh < 2; ++kh)
                rb0[n][kh] = lds_frag64(&sB[cur][0][0], wn * 32 + n * 16 + l16, kh * 4 + lhi);
        __builtin_amdgcn_s_setprio(1);
        #pragma unroll
        for (int m = 0; m < 4; ++m)
            #pragma unroll
            for (int n = 0; n < 2; ++n)
                #pragma unroll
                for (int kh = 0; kh < 2; ++kh)
                    acc[m][n] = __builtin_amdgcn_mfma_f32_16x16x32_bf16(
                        ra[m][kh], rb0[n][kh], acc[m][n], 0, 0, 0);
        __builtin_amdgcn_s_setprio(0);

        // P2
        if (t == NT - 1) asm volatile("s_waitcnt vmcnt(0)" ::: "memory");
        else             asm volatile("s_waitcnt vmcnt(8)" ::: "memory");
        __builtin_amdgcn_sched_barrier(0);
        __builtin_amdgcn_s_barrier();
        #pragma unroll
        for (int n = 0; n < 2; ++n)
            #pragma unroll
            for (int kh = 0; kh < 2; ++kh)
                rb[n][kh] = lds_frag64(&sB[cur][1][0], wn * 32 + n * 16 + l16, kh * 4 + lhi);
        __builtin_amdgcn_s_setprio(1);
        #pragma unroll
        for (int m = 0; m < 4; ++m)
            #pragma unroll
            for (int n = 0; n < 2; ++n)
                #pragma unroll
                for (int kh = 0; kh < 2; ++kh)
                    acc[m][n + 2] = __builtin_amdgcn_mfma_f32_16x16x32_bf16(
                        ra[m][kh], rb[n][kh], acc[m][n + 2], 0, 0, 0);
        __builtin_amdgcn_s_setprio(0);

        // P3 — stage {A0,B0}(t+2)
        if (t + 2 < NT) { stageA(cur, 0, t + 2); stageB(cur, 0, t + 2); }
        #pragma unroll
        for (int m = 0; m < 4; ++m)
            #pragma unroll
            for (int kh = 0; kh < 2; ++kh)
                ra[m][kh] = lds_frag64(&sA[cur][1][0], wm * 64 + m * 16 + l16, kh * 4 + lhi);
        __builtin_amdgcn_s_setprio(1);
        #pragma unroll
        for (int m = 0; m < 4; ++m)
            #pragma unroll
            for (int n = 0; n < 2; ++n)
                #pragma unroll
                for (int kh = 0; kh < 2; ++kh)
                    acc[m + 4][n + 2] = __builtin_amdgcn_mfma_f32_16x16x32_bf16(
                        ra[m][kh], rb[n][kh], acc[m + 4][n + 2], 0, 0, 0);
        __builtin_amdgcn_s_setprio(0);

        // P4 — pure MFMA
        __builtin_amdgcn_s_setprio(1);
        #pragma unroll
        for (int m = 0; m < 4; ++m)
            #pragma unroll
            for (int n = 0; n < 2; ++n)
                #pragma unroll
                for (int kh = 0; kh < 2; ++kh)
                    acc[m + 4][n] = __builtin_amdgcn_mfma_f32_16x16x32_bf16(
                        ra[m][kh], rb0[n][kh], acc[m + 4][n], 0, 0, 0);
        __builtin_amdgcn_s_setprio(0);
    }

    int crow = lhi * 4;
    #pragma unroll
    for (int qm = 0; qm < 2; ++qm)
        #pragma unroll
        for (int qn = 0; qn < 2; ++qn)
            #pragma unroll
            for (int m = 0; m < 4; ++m)
                #pragma unroll
                for (int n = 0; n < 2; ++n)
                    #pragma unroll
                    for (int r = 0; r < 4; ++r) {
                        size_t row = brow + qm * 128 + wm * 64 + m * 16 + crow + r;
                        size_t col = bcol + qn * 128 + wn * 32 + n * 16 + l16;
                        float val = acc[qm * 4 + m][qn * 2 + n][r];
                        val += bias[col];
                        outF[row * Nc + col] = val;
                    }
}

// ---------------------------------------------------------------------------
// 128x128 bf16 GEMM, BK=32, ring-of-4, prefetch depth 2 (QKV, W1)
// (round-15 verified; ring-3@3blk/CU regressed in round 16 — keep ring-4)
// ---------------------------------------------------------------------------
__launch_bounds__(256, 2)
__global__ void gemm_bf16_128(const bf16* __restrict__ A,
                              const bf16* __restrict__ Bt,
                              const float* __restrict__ bias,
                              const float* __restrict__ res,
                              float* __restrict__ outF,
                              bf16*  __restrict__ outB,
                              int M, int Nc, int K, int gelu_flag) {
    __shared__ __align__(16) bf16 sA[4][128 * 32];
    __shared__ __align__(16) bf16 sB[4][128 * 32];

    int tid  = threadIdx.x;
    int lane = tid & 63;
    int wid  = tid >> 6;
    int wr   = wid >> 1;
    int wc   = wid & 1;
    int l16  = lane & 15;
    int lhi  = lane >> 4;

    int nwg = gridDim.x * gridDim.y;
    int id  = blockIdx.y * gridDim.x + blockIdx.x;
    int cpx = nwg >> 3;
    int swz = (id & 7) * cpx + (id >> 3);
    int bx  = swz / gridDim.y;
    int by  = swz % gridDim.y;

    size_t brow = (size_t)by * 128;
    size_t bcol = (size_t)bx * 128;

    f32x4 acc[4][4] = {};

    auto stage = [&](int buf, int t) {
        size_t k0 = (size_t)t * 32;
        #pragma unroll
        for (int j = 0; j < 2; ++j) {
            int s = j * 256 + tid;
            int row = s >> 2;
            int ch  = (s & 3) ^ ((row >> 1) & 3);
            int ldso = (j * 256 + wid * 64) * 8;
            const bf16* ga = A + (brow + row) * K + k0 + ch * 8;
            __builtin_amdgcn_global_load_lds(
                (const AS1 void*)ga, (AS3 void*)(&sA[buf][0] + ldso), 16, 0, 0);
        }
        #pragma unroll
        for (int j = 0; j < 2; ++j) {
            int s = j * 256 + tid;
            int row = s >> 2;
            int ch  = (s & 3) ^ ((row >> 1) & 3);
            int ldso = (j * 256 + wid * 64) * 8;
            const bf16* gb = Bt + (bcol + row) * K + k0 + ch * 8;
            __builtin_amdgcn_global_load_lds(
                (const AS1 void*)gb, (AS3 void*)(&sB[buf][0] + ldso), 16, 0, 0);
        }
    };

    int NT = K / 32;
    stage(0, 0);
    stage(1, 1);

    for (int t = 0; t < NT; ++t) {
        if (t + 2 < NT) {
            stage((t + 2) & 3, t + 2);
            asm volatile("s_waitcnt vmcnt(8)" ::: "memory");
        } else if (t + 1 < NT) {
            asm volatile("s_waitcnt vmcnt(4)" ::: "memory");
        } else {
            asm volatile("s_waitcnt vmcnt(0)" ::: "memory");
        }
        __builtin_amdgcn_sched_barrier(0);
        __builtin_amdgcn_s_barrier();

        const bf16* As_ = &sA[t & 3][0];
        const bf16* Bs_ = &sB[t & 3][0];
        bf16x8 ra[4], rb[4];
        #pragma unroll
        for (int m = 0; m < 4; ++m)
            ra[m] = lds_frag32(As_, wr * 64 + m * 16 + l16, lhi);
        #pragma unroll
        for (int n = 0; n < 4; ++n)
            rb[n] = lds_frag32(Bs_, wc * 64 + n * 16 + l16, lhi);

        __builtin_amdgcn_s_setprio(1);
        #pragma unroll
        for (int m = 0; m < 4; ++m)
            #pragma unroll
            for (int n = 0; n < 4; ++n)
                acc[m][n] = __builtin_amdgcn_mfma_f32_16x16x32_bf16(
                    ra[m], rb[n], acc[m][n], 0, 0, 0);
        __builtin_amdgcn_s_setprio(0);
    }

    int crow = lhi * 4;
    #pragma unroll
    for (int m = 0; m < 4; ++m) {
        #pragma unroll
        for (int n = 0; n < 4; ++n) {
            #pragma unroll
            for (int r = 0; r < 4; ++r) {
                size_t row = brow + wr * 64 + m * 16 + crow + r;
                size_t col = bcol + wc * 64 + n * 16 + l16;
                float val = acc[m][n][r];
                if (bias) val += bias[col];
                if (gelu_flag) val = 0.5f * val * (1.0f + erff(val * 0.70710678118f));
                if (res) val += res[row * Nc + col];
                if (outF) outF[row * Nc + col] = val;
                if (outB) outB[row * Nc + col] = __float2bfloat16(val);
            }
        }
    }
}

// ---------------------------------------------------------------------------
// 64x128 bf16 GEMM, BK=64, ring-of-3 (verified round 11) (Wo, W2)
// ---------------------------------------------------------------------------
__launch_bounds__(256, 2)
__global__ void gemm_bf16_64(const bf16* __restrict__ A,
                             const bf16* __restrict__ Bt,
                             const float* __restrict__ bias,
                             const float* __restrict__ res,
                             float* __restrict__ outF,
                             bf16*  __restrict__ outB,
                             int M, int Nc, int K, int gelu_flag) {
    __shared__ __align__(16) bf16 sA[3][64 * 64];    // 3 x 8 KB
    __shared__ __align__(16) bf16 sB[3][128 * 64];   // 3 x 16 KB

    int tid  = threadIdx.x;
    int lane = tid & 63;
    int wid  = tid >> 6;
    int l16  = lane & 15;
    int lhi  = lane >> 4;

    int nwg = gridDim.x * gridDim.y;
    int id  = blockIdx.y * gridDim.x + blockIdx.x;
    int cpx = nwg >> 3;
    int swz = (id & 7) * cpx + (id >> 3);
    int bx  = swz / gridDim.y;
    int by  = swz % gridDim.y;

    size_t brow = (size_t)by * 64;
    size_t bcol = (size_t)bx * 128;

    f32x4 acc[4][2] = {};

    auto stage = [&](int buf, int t) {
        size_t k0 = (size_t)t * 64;
        #pragma unroll
        for (int j = 0; j < 2; ++j) {
            int s = j * 256 + tid;
            int row = s >> 3;
            int ch  = (s & 7) ^ (row & 7);
            int ldso = (j * 256 + wid * 64) * 8;
            const bf16* ga = A + (brow + row) * K + k0 + ch * 8;
            __builtin_amdgcn_global_load_lds(
                (const AS1 void*)ga, (AS3 void*)(&sA[buf][0] + ldso), 16, 0, 0);
        }
        #pragma unroll
        for (int j = 0; j < 4; ++j) {
            int s = j * 256 + tid;
            int row = s >> 3;
            int ch  = (s & 7) ^ (row & 7);
            int ldso = (j * 256 + wid * 64) * 8;
            const bf16* gb = Bt + (bcol + row) * K + k0 + ch * 8;
            __builtin_amdgcn_global_load_lds(
                (const AS1 void*)gb, (AS3 void*)(&sB[buf][0] + ldso), 16, 0, 0);
        }
    };

    int NT = K / 64;
    stage(0, 0); stage(1, 1);
    int cur = 0, sl2 = 2;

    for (int t = 0; t < NT; ++t) {
        if (t == NT - 1) asm volatile("s_waitcnt vmcnt(0)" ::: "memory");
        else             asm volatile("s_waitcnt vmcnt(6)" ::: "memory");
        __builtin_amdgcn_sched_barrier(0);
        __builtin_amdgcn_s_barrier();
        if (t + 2 < NT) stage(sl2, t + 2);

        const bf16* As_ = &sA[cur][0];
        const bf16* Bs_ = &sB[cur][0];
        bf16x8 ra[4][2], rb[2][2];
        #pragma unroll
        for (int m = 0; m < 4; ++m)
            #pragma unroll
            for (int kh = 0; kh < 2; ++kh)
                ra[m][kh] = lds_frag64(As_, m * 16 + l16, kh * 4 + lhi);
        #pragma unroll
        for (int n = 0; n < 2; ++n)
            #pragma unroll
            for (int kh = 0; kh < 2; ++kh)
                rb[n][kh] = lds_frag64(Bs_, wid * 32 + n * 16 + l16, kh * 4 + lhi);

        __builtin_amdgcn_s_setprio(1);
        #pragma unroll
        for (int m = 0; m < 4; ++m)
            #pragma unroll
            for (int n = 0; n < 2; ++n)
                #pragma unroll
                for (int kh = 0; kh < 2; ++kh)
                    acc[m][n] = __builtin_amdgcn_mfma_f32_16x16x32_bf16(
                        ra[m][kh], rb[n][kh], acc[m][n], 0, 0, 0);
        __builtin_amdgcn_s_setprio(0);

        cur = (cur == 2) ? 0 : cur + 1;
        sl2 = (sl2 == 2) ? 0 : sl2 + 1;
    }

    int crow = lhi * 4;
    #pragma unroll
    for (int m = 0; m < 4; ++m) {
        #pragma unroll
        for (int n = 0; n < 2; ++n) {
            #pragma unroll
            for (int r = 0; r < 4; ++r) {
                size_t row = brow + m * 16 + crow + r;
                size_t col = bcol + wid * 32 + n * 16 + l16;
                float val = acc[m][n][r];
                if (bias) val += bias[col];
                if (gelu_flag) val = 0.5f * val * (1.0f + erff(val * 0.70710678118f));
                if (res) val += res[row * Nc + col];
                if (outF) outF[row * Nc + col] = val;
                if (outB) outB[row * Nc + col] = __float2bfloat16(val);
            }
        }
    }
}

// ---------------------------------------------------------------------------
// Flash attention (round 15): fused V-transpose staging, balance swizzle,
// reg-staged K/V prefetch. QBLK=64, 4 waves.
// ---------------------------------------------------------------------------
constexpr int QBLK = 64;
constexpr int KVB  = 64;
constexpr int PSTR = 72;

__launch_bounds__(256)
__global__ void flash_attn(const bf16* __restrict__ qkv,
                           bf16* __restrict__ O) {
    __shared__ bf16 sK[KVB][PSTR];
    __shared__ bf16 sV[D][PSTR];
    __shared__ bf16 sP[4][16][PSTR];

    int qt = blockIdx.x;
    int bh = blockIdx.y;
    if (bh & 1) qt = (C / QBLK - 1) - qt;
    int bb = bh >> 4, hh = bh & 15;
    int qbase = qt * QBLK;
    int tid = threadIdx.x, lane = tid & 63, w = tid >> 6;
    int l16 = lane & 15, lhi = lane >> 4;

    int qrow = qbase + w * 16 + l16;
    const bf16* qp = qkv + (size_t)(bb * C + qrow) * E3 + hh * D + lhi * 8;
    bf16x8 qf0 = *(const bf16x8*)qp;
    bf16x8 qf1 = *(const bf16x8*)(qp + 32);

    f32x4 oa[4] = {};
    float m_run[4] = {-INFINITY, -INFINITY, -INFINITY, -INFINITY};
    float l_run[4] = {0.f, 0.f, 0.f, 0.f};

    int NTk = qt + 1;
    int srow = tid >> 3, sc8 = tid & 7;
    int srow2 = srow + 32;
    int c1 = srow  ^ (sc8 << 3);
    int c2 = srow2 ^ (sc8 << 3);

    bf16x8 kvR0, kvR1, vvR0, vvR1;
    kvR0 = *(const bf16x8*)(qkv + (size_t)(bb * C + srow)  * E3 + E + hh * D + sc8 * 8);
    kvR1 = *(const bf16x8*)(qkv + (size_t)(bb * C + srow2) * E3 + E + hh * D + sc8 * 8);
    vvR0 = *(const bf16x8*)(qkv + (size_t)(bb * C + srow)  * E3 + 2 * E + hh * D + sc8 * 8);
    vvR1 = *(const bf16x8*)(qkv + (size_t)(bb * C + srow2) * E3 + 2 * E + hh * D + sc8 * 8);

    for (int t = 0; t < NTk; ++t) {
        __syncthreads();
        lds_store8(&sK[srow][sc8 * 8],  kvR0);
        lds_store8(&sK[srow2][sc8 * 8], kvR1);
        #pragma unroll
        for (int j = 0; j < 8; ++j) {
            *((__bf16*)&sV[sc8 * 8 + j][c1]) = vvR0[j];
            *((__bf16*)&sV[sc8 * 8 + j][c2]) = vvR1[j];
        }

        bf16x8 kvN0, kvN1, vvN0, vvN1;
        if (t + 1 < NTk) {
            int k0n = (t + 1) * KVB;
            kvN0 = *(const bf16x8*)(qkv + (size_t)(bb * C + k0n + srow)  * E3 + E + hh * D + sc8 * 8);
            kvN1 = *(const bf16x8*)(qkv + (size_t)(bb * C + k0n + srow2) * E3 + E + hh * D + sc8 * 8);
            vvN0 = *(const bf16x8*)(qkv + (size_t)(bb * C + k0n + srow)  * E3 + 2 * E + hh * D + sc8 * 8);
            vvN1 = *(const bf16x8*)(qkv + (size_t)(bb * C + k0n + srow2) * E3 + 2 * E + hh * D + sc8 * 8);
        }
        __syncthreads();

        int k0 = t * KVB;
        f32x4 sc[4] = {};
        #pragma unroll
        for (int n = 0; n < 4; ++n) {
            bf16x8 kf0 = lds_load8(&sK[n * 16 + l16][lhi * 8]);
            sc[n] = __builtin_amdgcn_mfma_f32_16x16x32_bf16(qf0, kf0, sc[n], 0, 0, 0);
            bf16x8 kf1 = lds_load8(&sK[n * 16 + l16][32 + lhi * 8]);
            sc[n] = __builtin_amdgcn_mfma_f32_16x16x32_bf16(qf1, kf1, sc[n], 0, 0, 0);
        }

        int qg = qbase + w * 16 + lhi * 4;
        #pragma unroll
        for (int n = 0; n < 4; ++n) {
            int kg = k0 + n * 16 + l16;
            #pragma unroll
            for (int r = 0; r < 4; ++r) {
                float vvv = sc[n][r] * 0.125f;
                if (t == qt && kg > qg + r) vvv = -1e30f;
                sc[n][r] = vvv;
            }
        }

        float pm[4];
        #pragma unroll
        for (int r = 0; r < 4; ++r)
            pm[r] = fmaxf(fmaxf(sc[0][r], sc[1][r]), fmaxf(sc[2][r], sc[3][r]));
        #pragma unroll
        for (int xm = 1; xm <= 8; xm <<= 1)
            #pragma unroll
            for (int r = 0; r < 4; ++r)
                pm[r] = fmaxf(pm[r], __shfl_xor(pm[r], xm));

        float corr[4];
        #pragma unroll
        for (int r = 0; r < 4; ++r) {
            float mn = fmaxf(m_run[r], pm[r]);
            corr[r] = __expf(m_run[r] - mn);
            m_run[r] = mn;
        }
        f32x4 p[4];
        #pragma unroll
        for (int n = 0; n < 4; ++n)
            #pragma unroll
            for (int r = 0; r < 4; ++r)
                p[n][r] = __expf(sc[n][r] - m_run[r]);

        float rsum[4];
        #pragma unroll
        for (int r = 0; r < 4; ++r)
            rsum[r] = p[0][r] + p[1][r] + p[2][r] + p[3][r];
        #pragma unroll
        for (int xm = 1; xm <= 8; xm <<= 1)
            #pragma unroll
            for (int r = 0; r < 4; ++r)
                rsum[r] += __shfl_xor(rsum[r], xm);
        #pragma unroll
        for (int r = 0; r < 4; ++r)
            l_run[r] = l_run[r] * corr[r] + rsum[r];
        #pragma unroll
        for (int nd = 0; nd < 4; ++nd)
            #pragma unroll
            for (int r = 0; r < 4; ++r)
                oa[nd][r] *= corr[r];

        #pragma unroll
        for (int n = 0; n < 4; ++n)
            #pragma unroll
            for (int r = 0; r < 4; ++r)
                sP[w][lhi * 4 + r][n * 16 + l16] = __float2bfloat16(p[n][r]);
        bf16x8 pa0 = lds_load8(&sP[w][l16][lhi * 8]);
        bf16x8 pa1 = lds_load8(&sP[w][l16][32 + lhi * 8]);

        #pragma unroll
        for (int nd = 0; nd < 4; ++nd) {
            int d0 = nd * 16 + l16;
            int dsw = ((nd * 2 + (l16 >> 3)) & 7) << 3;
            bf16x8 vf0 = lds_load8(&sV[d0][(lhi * 8) ^ dsw]);
            oa[nd] = __builtin_amdgcn_mfma_f32_16x16x32_bf16(pa0, vf0, oa[nd], 0, 0, 0);
            bf16x8 vf1 = lds_load8(&sV[d0][(32 + lhi * 8) ^ dsw]);
            oa[nd] = __builtin_amdgcn_mfma_f32_16x16x32_bf16(pa1, vf1, oa[nd], 0, 0, 0);
        }

        if (t + 1 < NTk) { kvR0 = kvN0; kvR1 = kvN1; vvR0 = vvN0; vvR1 = vvN1; }
    }

    #pragma unroll
    for (int r = 0; r < 4; ++r) {
        float inv = 1.0f / l_run[r];
        int qg = qbase + w * 16 + lhi * 4 + r;
        bf16* orow = O + (size_t)(bb * C + qg) * E + hh * D;
        #pragma unroll
        for (int nd = 0; nd < 4; ++nd)
            orow[nd * 16 + l16] = __float2bfloat16(oa[nd][r] * inv);
    }
}

// ---------------------------------------------------------------------------
extern "C" void kernel_launch(void* const* d_in, const int* in_sizes, int n_in,
                              void* d_out, int out_size, void* d_ws, size_t ws_size,
                              hipStream_t stream) {
    const int*   x     = (const int*)  d_in[0];
    const float* embed = (const float*)d_in[1];
    const float* pos   = (const float*)d_in[2];
    const float* Wq    = (const float*)d_in[3];
    const float* Wk    = (const float*)d_in[4];
    const float* Wv    = (const float*)d_in[5];
    const float* Wo    = (const float*)d_in[6];
    const float* ln1w  = (const float*)d_in[7];
    const float* ln1b  = (const float*)d_in[8];
    const float* ln2w  = (const float*)d_in[9];
    const float* ln2b  = (const float*)d_in[10];
    const float* W1    = (const float*)d_in[11];
    const float* b1    = (const float*)d_in[12];
    const float* W2    = (const float*)d_in[13];
    const float* b2    = (const float*)d_in[14];
    const float* lnfw  = (const float*)d_in[15];
    const float* lnfb  = (const float*)d_in[16];
    const float* Wout  = (const float*)d_in[17];
    const float* bout  = (const float*)d_in[18];
    float* out = (float*)d_out;

    char* p = (char*)d_ws;
    auto alloc = [&](size_t bytes) {
        char* r = p;
        p += (bytes + 255) & ~(size_t)255;
        return r;
    };
    float* h    = (float*)alloc((size_t)N * E  * 4);
    bf16*  qkvb = (bf16*) alloc((size_t)N * E3 * 2);
    bf16*  hn   = (bf16*) alloc((size_t)N * E  * 2);
    bf16*  attn = (bf16*) alloc((size_t)N * E  * 2);
    bf16*  ff   = (bf16*) alloc((size_t)N * FF * 2);
    bf16*  qkvt = (bf16*) alloc((size_t)L * E3 * E * 2);
    bf16*  wot  = (bf16*) alloc((size_t)L * E  * E * 2);
    bf16*  w1t  = (bf16*) alloc((size_t)L * FF * E * 2);
    bf16*  w2t  = (bf16*) alloc((size_t)L * E  * FF * 2);
    bf16*  wvt  = (bf16*) alloc((size_t)V * E  * 2 + 4096);

    transpose_all<<<20288, 256, 0, stream>>>(Wq, Wk, Wv, Wo, W1, W2, Wout,
                                             qkvt, wot, w1t, w2t, wvt);

    embed_ln_kernel<<<N, 256, 0, stream>>>(x, embed, pos, ln1w, ln1b, h, hn);

    dim3 gQKV(E3 / 128, N / 128);   // (24, 16) = 384 blocks
    dim3 gF  (FF / 128, N / 128);   // (32, 16) = 512
    dim3 gV  (V  / 256, N / 256);   // (125, 8) = 1000, 8-phase 256^2 BK=64
    dim3 gO  (E  / 128, N / 64);    // (8, 32)  = 256, BK=64 ring-3

    for (int i = 0; i < L; ++i) {
        if (i > 0)
            layernorm_kernel<<<N, 256, 0, stream>>>(h, ln1w + i * E, ln1b + i * E, hn);

        gemm_bf16_128<<<gQKV, 256, 0, stream>>>(hn, qkvt + (size_t)i * E3 * E,
                                                nullptr, nullptr, nullptr, qkvb,
                                                N, E3, E, 0);

        flash_attn<<<dim3(C / QBLK, B * H), 256, 0, stream>>>(qkvb, attn);

        gemm_bf16_64<<<gO, 256, 0, stream>>>(attn, wot + (size_t)i * E * E,
                                             nullptr, h, h, nullptr,
                                             N, E, E, 0);

        layernorm_kernel<<<N, 256, 0, stream>>>(h, ln2w + i * E, ln2b + i * E, hn);

        gemm_bf16_128<<<gF, 256, 0, stream>>>(hn, w1t + (size_t)i * FF * E,
                                              b1 + (size_t)i * FF, nullptr,
                                              nullptr, ff,
                                              N, FF, E, 1);
        gemm_bf16_64<<<gO, 256, 0, stream>>>(ff, w2t + (size_t)i * E * FF,
                                             b2 + (size_t)i * E, h, h, nullptr,
                                             N, E, FF, 0);
    }

    layernorm_kernel<<<N, 256, 0, stream>>>(h, lnfw, lnfb, hn);
    gemm_v8<<<gV, 512, 0, stream>>>(hn, wvt, bout, out, N, V, E);
}